// Round 1
// baseline (564.796 us; speedup 1.0000x reference)
//
#include <hip/hip_runtime.h>
#include <hip/hip_bf16.h>

typedef __bf16 bf16x8 __attribute__((ext_vector_type(8)));
typedef float f32x4 __attribute__((ext_vector_type(4)));

#define DEVI static __device__ __forceinline__

DEVI void load_lds16(const void* g, void* l) {
  __builtin_amdgcn_global_load_lds(
      (const __attribute__((address_space(1))) void*)g,
      (__attribute__((address_space(3))) void*)l, 16, 0, 0);
}

DEVI unsigned short f2b(float f) { return __bfloat16_as_ushort(__float2bfloat16(f)); }
DEVI float b2f(unsigned short u) {
  union { unsigned int i; float f; } c;
  c.i = ((unsigned int)u) << 16;
  return c.f;
}
DEVI float sigm(float x) { return 1.0f / (1.0f + __expf(-x)); }
DEVI float tanh_fast(float x) { return 2.0f / (1.0f + __expf(-2.0f * x)) - 1.0f; }

// ---------------------------------------------------------------- cast fp32->bf16
__global__ __launch_bounds__(256) void cast_kernel(const float* __restrict__ src,
                                                   unsigned short* __restrict__ dst,
                                                   int n4) {
  const int i = blockIdx.x * 256 + threadIdx.x;
  if (i >= n4) return;
  const float4 v = reinterpret_cast<const float4*>(src)[i];
  ushort4 o;
  o.x = f2b(v.x); o.y = f2b(v.y); o.z = f2b(v.z); o.w = f2b(v.w);
  reinterpret_cast<ushort4*>(dst)[i] = o;
}

// ---------------------------------------------------------------- GEMM
// C[M=4096, N=4096] = A[M, K=1024] * Bm[N, K=1024]^T   (all bf16 bits, fp32 acc)
// 128x128 tile, BK=32, 4 waves (2x2 of 64x64), 16x16x32 bf16 MFMA,
// global_load_lds width-16 staging (m97 structure).
__global__ __launch_bounds__(256) void gemm_bt_128(
    const unsigned short* __restrict__ A,
    const unsigned short* __restrict__ Bm,
    unsigned short* __restrict__ C) {
  constexpr int K = 1024, N = 4096, BK = 32;
  __shared__ unsigned short As[128 * BK];
  __shared__ unsigned short Bs[128 * BK];

  const int tid = threadIdx.x;
  const int lane = tid & 63;
  const int wave = tid >> 6;
  const int wr = wave >> 1, wc = wave & 1;
  const int brow = blockIdx.y * 128, bcol = blockIdx.x * 128;

  f32x4 acc[4][4] = {};

  // staging geometry: each thread loads 16B (8 bf16), row = tid/4, col8 = (tid%3)*8
  const int srow = tid >> 2;          // 0..63
  const int sc8 = (tid & 3) * 8;      // 0,8,16,24
  const int grA = brow + srow;
  const int grB = bcol + srow;

  // fragment geometry
  const int lr = lane & 15;
  const int lk = (lane >> 4) * 8;

  for (int kt = 0; kt < K; kt += BK) {
    load_lds16(&A[(grA)*K + kt + sc8], &As[(srow)*BK + sc8]);
    load_lds16(&A[(grA + 64) * K + kt + sc8], &As[(srow + 64) * BK + sc8]);
    load_lds16(&Bm[(grB)*K + kt + sc8], &Bs[(srow)*BK + sc8]);
    load_lds16(&Bm[(grB + 64) * K + kt + sc8], &Bs[(srow + 64) * BK + sc8]);
    __syncthreads();  // drains vmcnt -> staged data visible

    bf16x8 af[4], bfr[4];
#pragma unroll
    for (int m = 0; m < 4; ++m)
      af[m] = *reinterpret_cast<const bf16x8*>(&As[(wr * 64 + m * 16 + lr) * BK + lk]);
#pragma unroll
    for (int n = 0; n < 4; ++n)
      bfr[n] = *reinterpret_cast<const bf16x8*>(&Bs[(wc * 64 + n * 16 + lr) * BK + lk]);

#pragma unroll
    for (int m = 0; m < 4; ++m)
#pragma unroll
      for (int n = 0; n < 4; ++n)
        acc[m][n] = __builtin_amdgcn_mfma_f32_16x16x32_bf16(af[m], bfr[n], acc[m][n], 0, 0, 0);
    __syncthreads();  // all waves done reading before next stage
  }

  // epilogue: C/D layout col=lane&15, row=(lane>>4)*4+reg  (m89-verified)
  const int crow0 = (lane >> 4) * 4;
  const int ccol = lane & 15;
#pragma unroll
  for (int m = 0; m < 4; ++m)
#pragma unroll
    for (int n = 0; n < 4; ++n) {
      const int gcol = bcol + wc * 64 + n * 16 + ccol;
#pragma unroll
      for (int r = 0; r < 4; ++r) {
        const int grow = brow + wr * 64 + m * 16 + crow0 + r;
        C[(size_t)grow * N + gcol] = f2b(acc[m][n][r]);
      }
    }
}

// ---------------------------------------------------------------- gates
// per element (b,h): f,i,o,g from xproj/hproj[b, g*H+h] + bW + bU; update ct, ht.
template <bool FIRST, bool LAST>
__global__ __launch_bounds__(256) void gates_kernel(
    const unsigned short* __restrict__ xproj,  // [B,4H] bf16
    const unsigned short* __restrict__ hproj,  // [B,4H] bf16 (ignored if FIRST)
    const float* __restrict__ bW,              // [4H]
    const float* __restrict__ bU,              // [4H]
    float* __restrict__ ct,                    // [B,H] fp32 state
    unsigned short* __restrict__ ht,           // [B,H] bf16 (next-step GEMM input)
    float* __restrict__ out) {                 // d_out when LAST: [ht | ct] fp32
  const int i = blockIdx.x * 256 + threadIdx.x;  // one thread = 4 h's
  const int b = i >> 8;
  const int h0 = (i & 255) << 2;
  const size_t base = (size_t)b * 4096 + h0;

  float s[4][4];
#pragma unroll
  for (int g = 0; g < 4; ++g) {
    const ushort4 xv = *reinterpret_cast<const ushort4*>(&xproj[base + g * 1024]);
    const float4 bw = *reinterpret_cast<const float4*>(&bW[g * 1024 + h0]);
    const float4 bu = *reinterpret_cast<const float4*>(&bU[g * 1024 + h0]);
    s[g][0] = b2f(xv.x) + bw.x + bu.x;
    s[g][1] = b2f(xv.y) + bw.y + bu.y;
    s[g][2] = b2f(xv.z) + bw.z + bu.z;
    s[g][3] = b2f(xv.w) + bw.w + bu.w;
    if (!FIRST) {
      const ushort4 hv = *reinterpret_cast<const ushort4*>(&hproj[base + g * 1024]);
      s[g][0] += b2f(hv.x);
      s[g][1] += b2f(hv.y);
      s[g][2] += b2f(hv.z);
      s[g][3] += b2f(hv.w);
    }
  }

  const int cidx = b * 1024 + h0;
  float co[4] = {0.f, 0.f, 0.f, 0.f};
  if (!FIRST) {
    const float4 cold = *reinterpret_cast<const float4*>(&ct[cidx]);
    co[0] = cold.x; co[1] = cold.y; co[2] = cold.z; co[3] = cold.w;
  }

  float cn[4], hn[4];
#pragma unroll
  for (int j = 0; j < 4; ++j) {
    const float f = sigm(s[0][j]);
    const float ii = sigm(s[1][j]);
    const float o = sigm(s[2][j]);
    const float gg = tanh_fast(s[3][j]);
    const float c = fmaf(f, co[j], ii * gg);
    cn[j] = c;
    hn[j] = o * tanh_fast(c);
  }

  *reinterpret_cast<float4*>(&ct[cidx]) = make_float4(cn[0], cn[1], cn[2], cn[3]);
  if (!LAST) {
    ushort4 hb;
    hb.x = f2b(hn[0]); hb.y = f2b(hn[1]); hb.z = f2b(hn[2]); hb.w = f2b(hn[3]);
    *reinterpret_cast<ushort4*>(&ht[cidx]) = hb;
  } else {
    *reinterpret_cast<float4*>(&out[cidx]) = make_float4(hn[0], hn[1], hn[2], hn[3]);
    *reinterpret_cast<float4*>(&out[4194304 + cidx]) = make_float4(cn[0], cn[1], cn[2], cn[3]);
  }
}

// ---------------------------------------------------------------- launch
extern "C" void kernel_launch(void* const* d_in, const int* in_sizes, int n_in,
                              void* d_out, int out_size, void* d_ws, size_t ws_size,
                              hipStream_t stream) {
  const float* x = (const float*)d_in[0];   // [4096,1024]
  const float* W = (const float*)d_in[1];   // [4096,1024]
  const float* bW = (const float*)d_in[2];  // [4096]
  const float* U = (const float*)d_in[3];   // [4096,1024]
  const float* bU = (const float*)d_in[4];  // [4096]
  float* out = (float*)d_out;

  char* w = (char*)d_ws;
  const size_t MB = 1ull << 20;
  unsigned short* xb = (unsigned short*)(w + 0 * MB);      // 8 MB
  unsigned short* Wb = (unsigned short*)(w + 8 * MB);      // 8 MB
  unsigned short* Ub = (unsigned short*)(w + 16 * MB);     // 8 MB
  unsigned short* xproj = (unsigned short*)(w + 24 * MB);  // 32 MB [B,4H] bf16
  unsigned short* hproj = (unsigned short*)(w + 56 * MB);  // 32 MB
  float* ct = (float*)(w + 88 * MB);                       // 16 MB
  unsigned short* ht = (unsigned short*)(w + 104 * MB);    // 8 MB  (112 MB total)

  const int n4 = (4096 * 1024) / 4;
  cast_kernel<<<n4 / 256, 256, 0, stream>>>(x, xb, n4);
  cast_kernel<<<n4 / 256, 256, 0, stream>>>(W, Wb, n4);
  cast_kernel<<<n4 / 256, 256, 0, stream>>>(U, Ub, n4);

  dim3 ggrid(32, 32);
  gemm_bt_128<<<ggrid, 256, 0, stream>>>(xb, Wb, xproj);
  gates_kernel<true, false><<<4096, 256, 0, stream>>>(xproj, nullptr, bW, bU, ct, ht, nullptr);
  for (int t = 1; t < 8; ++t) {
    gemm_bt_128<<<ggrid, 256, 0, stream>>>(ht, Ub, hproj);
    if (t == 7)
      gates_kernel<false, true><<<4096, 256, 0, stream>>>(xproj, hproj, bW, bU, ct, ht, out);
    else
      gates_kernel<false, false><<<4096, 256, 0, stream>>>(xproj, hproj, bW, bU, ct, ht, nullptr);
  }
}

// Round 3
// 458.077 us; speedup vs baseline: 1.2330x; 1.2330x over previous
//
#include <hip/hip_runtime.h>
#include <hip/hip_bf16.h>

typedef __bf16 bf16x8 __attribute__((ext_vector_type(8)));
typedef float f32x4 __attribute__((ext_vector_type(4)));

#define DEVI static __device__ __forceinline__

DEVI void load_lds16(const void* g, void* l) {
  __builtin_amdgcn_global_load_lds(
      (const __attribute__((address_space(1))) void*)g,
      (__attribute__((address_space(3))) void*)l, 16, 0, 0);
}

DEVI unsigned short f2b(float f) { return __bfloat16_as_ushort(__float2bfloat16(f)); }
DEVI float b2f(unsigned short u) {
  union { unsigned int i; float f; } c;
  c.i = ((unsigned int)u) << 16;
  return c.f;
}
DEVI float sigm(float x) { return 1.0f / (1.0f + __expf(-x)); }
DEVI float tanh_fast(float x) { return 2.0f / (1.0f + __expf(-2.0f * x)) - 1.0f; }

// involutive 16B-granule swizzle within a 32KB slot: XOR byte-bits 4-6 with bits 7-9.
// Bits 7-9 are untouched by the XOR -> involution. Keeps 16B alignment.
DEVI int swz(int L) { return L ^ (((L >> 7) & 7) << 4); }

// ---------------------------------------------------------------- cast fp32->bf16
__global__ __launch_bounds__(256) void cast_kernel(const float* __restrict__ src,
                                                   unsigned short* __restrict__ dst,
                                                   int n4) {
  const int i = blockIdx.x * 256 + threadIdx.x;
  if (i >= n4) return;
  const float4 v = reinterpret_cast<const float4*>(src)[i];
  ushort4 o;
  o.x = f2b(v.x); o.y = f2b(v.y); o.z = f2b(v.z); o.w = f2b(v.w);
  reinterpret_cast<ushort4*>(dst)[i] = o;
}

// ---------------------------------------------------------------- GEMM 256x256
// C[4096,4096] = A[4096,1024] * Bm[4096,1024]^T (bf16 in, fp32 acc, bf16 out)
// 8 waves (2M x 4N), per-wave 128x64. K phased in 32-element halves:
// 4 LDS slots x 32KB (A 16KB | B 16KB), phase p computes slot p&3 while
// staging phase p+3 into slot (p+3)&3 (freed at the previous barrier).
// Counted vmcnt(8) at boundaries -> 8 loads always in flight (T3+T4).
__global__ __launch_bounds__(512, 2) void gemm256(
    const unsigned short* __restrict__ A,
    const unsigned short* __restrict__ Bm,
    unsigned short* __restrict__ C) {
  constexpr int K = 1024, N = 4096;
  constexpr int NPH = K / 32;  // 32 phases
  __shared__ unsigned char lds[4 * 32768];

  const int tid = threadIdx.x;
  const int lane = tid & 63;
  const int wave = tid >> 6;
  const int wr = wave >> 2;  // 0..1 : M half (128 rows)
  const int wc = wave & 3;   // 0..3 : N quarter (64 cols)

  // XCD-aware block swizzle (nwg=256, divisible by 8 -> simple form)
  const int bid = blockIdx.x;
  const int sw = (bid & 7) * 32 + (bid >> 3);
  const int brow = (sw >> 4) * 256;
  const int bcol = (sw & 15) * 256;

  // ---- staging geometry: 4 x 16B loads per thread per phase.
  // Slot layout (physical): A bytes [0,16384) = 256 rows x 64B, B bytes [16384,32768).
  // LDS dest is linear (wave-uniform base + lane*16); the swizzle is applied by
  // pre-permuting the per-lane GLOBAL source (rule #21).
  const int physA0 = tid * 16;
  const int physA1 = 8192 + tid * 16;
  const int physB0 = 16384 + tid * 16;
  const int physB1 = 24576 + tid * 16;
  const int LA0 = swz(physA0), LA1 = swz(physA1);
  const int LB0 = swz(physB0 - 16384), LB1 = swz(physB1 - 16384);
  // row = L>>6 (64B logical rows), kbyte = L&63
  const unsigned char* pA0 = (const unsigned char*)A + (size_t)(brow + (LA0 >> 6)) * (K * 2) + (LA0 & 63);
  const unsigned char* pA1 = (const unsigned char*)A + (size_t)(brow + (LA1 >> 6)) * (K * 2) + (LA1 & 63);
  const unsigned char* pB0 = (const unsigned char*)Bm + (size_t)(bcol + (LB0 >> 6)) * (K * 2) + (LB0 & 63);
  const unsigned char* pB1 = (const unsigned char*)Bm + (size_t)(bcol + (LB1 >> 6)) * (K * 2) + (LB1 & 63);

  // ---- fragment read offsets (slot-relative physical), swizzled
  const int s16 = (lane >> 4) * 16;  // 16B k-slot within the 64B row
  int offA[8], offB[4];
#pragma unroll
  for (int m = 0; m < 8; ++m) {
    const int row = wr * 128 + m * 16 + (lane & 15);
    offA[m] = swz(row * 64 + s16);
  }
#pragma unroll
  for (int n = 0; n < 4; ++n) {
    const int row = wc * 64 + n * 16 + (lane & 15);
    offB[n] = 16384 + swz(row * 64 + s16);
  }

  f32x4 acc[8][4] = {};

  auto STAGE = [&](int q) {
    unsigned char* sb = lds + (q & 3) * 32768;
    const size_t kb = (size_t)q * 64;  // K advances 32 elems = 64B per phase
    load_lds16(pA0 + kb, sb + physA0);
    load_lds16(pA1 + kb, sb + physA1);
    load_lds16(pB0 + kb, sb + physB0);
    load_lds16(pB1 + kb, sb + physB1);
  };

  // prologue: 3 phases in flight; wait for phase 0 only (8 newest stay out)
  STAGE(0); STAGE(1); STAGE(2);
  asm volatile("s_waitcnt vmcnt(8)" ::: "memory");
  __builtin_amdgcn_s_barrier();
  __builtin_amdgcn_sched_barrier(0);

  for (int p = 0; p < NPH; ++p) {
    if (p + 3 < NPH) STAGE(p + 3);

    const unsigned char* sl = lds + (p & 3) * 32768;
    bf16x8 af[8], bf[4];
#pragma unroll
    for (int n = 0; n < 4; ++n) bf[n] = *reinterpret_cast<const bf16x8*>(sl + offB[n]);
#pragma unroll
    for (int m = 0; m < 8; ++m) af[m] = *reinterpret_cast<const bf16x8*>(sl + offA[m]);

    __builtin_amdgcn_s_setprio(1);
#pragma unroll
    for (int m = 0; m < 8; ++m)
#pragma unroll
      for (int n = 0; n < 4; ++n)
        acc[m][n] = __builtin_amdgcn_mfma_f32_16x16x32_bf16(af[m], bf[n], acc[m][n], 0, 0, 0);
    __builtin_amdgcn_s_setprio(0);

    if (p < NPH - 1) {
      // boundary: need phase p+1's loads landed (all waves). Newest 8 (phases
      // p+2, p+3) may stay in flight; tail drains 8 -> 4 -> 0.
      if (p < NPH - 3)
        asm volatile("s_waitcnt vmcnt(8)" ::: "memory");
      else if (p == NPH - 3)
        asm volatile("s_waitcnt vmcnt(4)" ::: "memory");
      else
        asm volatile("s_waitcnt vmcnt(0)" ::: "memory");
      __builtin_amdgcn_s_barrier();
      __builtin_amdgcn_sched_barrier(0);
    }
  }

  // epilogue: C/D layout col=lane&15, row=(lane>>4)*4+reg (m89-verified)
  const int crow0 = (lane >> 4) * 4;
  const int ccol = lane & 15;
#pragma unroll
  for (int m = 0; m < 8; ++m)
#pragma unroll
    for (int n = 0; n < 4; ++n) {
      const int gcol = bcol + wc * 64 + n * 16 + ccol;
#pragma unroll
      for (int r = 0; r < 4; ++r) {
        const int grow = brow + wr * 128 + m * 16 + crow0 + r;
        C[(size_t)grow * N + gcol] = f2b(acc[m][n][r]);
      }
    }
}

// ---------------------------------------------------------------- gates
template <bool FIRST, bool LAST>
__global__ __launch_bounds__(256) void gates_kernel(
    const unsigned short* __restrict__ xproj,  // [B,4H] bf16
    const unsigned short* __restrict__ hproj,  // [B,4H] bf16 (ignored if FIRST)
    const float* __restrict__ bW,              // [4H]
    const float* __restrict__ bU,              // [4H]
    float* __restrict__ ct,                    // [B,H] fp32 state
    unsigned short* __restrict__ ht,           // [B,H] bf16
    float* __restrict__ out) {                 // d_out when LAST: [ht | ct] fp32
  const int i = blockIdx.x * 256 + threadIdx.x;  // one thread = 4 h's
  const int b = i >> 8;
  const int h0 = (i & 255) << 2;
  const size_t base = (size_t)b * 4096 + h0;

  float s[4][4];
#pragma unroll
  for (int g = 0; g < 4; ++g) {
    const ushort4 xv = *reinterpret_cast<const ushort4*>(&xproj[base + g * 1024]);
    const float4 bw = *reinterpret_cast<const float4*>(&bW[g * 1024 + h0]);
    const float4 bu = *reinterpret_cast<const float4*>(&bU[g * 1024 + h0]);
    s[g][0] = b2f(xv.x) + bw.x + bu.x;
    s[g][1] = b2f(xv.y) + bw.y + bu.y;
    s[g][2] = b2f(xv.z) + bw.z + bu.z;
    s[g][3] = b2f(xv.w) + bw.w + bu.w;
    if (!FIRST) {
      const ushort4 hv = *reinterpret_cast<const ushort4*>(&hproj[base + g * 1024]);
      s[g][0] += b2f(hv.x);
      s[g][1] += b2f(hv.y);
      s[g][2] += b2f(hv.z);
      s[g][3] += b2f(hv.w);
    }
  }

  const int cidx = b * 1024 + h0;
  float co[4] = {0.f, 0.f, 0.f, 0.f};
  if (!FIRST) {
    const float4 cold = *reinterpret_cast<const float4*>(&ct[cidx]);
    co[0] = cold.x; co[1] = cold.y; co[2] = cold.z; co[3] = cold.w;
  }

  float cn[4], hn[4];
#pragma unroll
  for (int j = 0; j < 4; ++j) {
    const float f = sigm(s[0][j]);
    const float ii = sigm(s[1][j]);
    const float o = sigm(s[2][j]);
    const float gg = tanh_fast(s[3][j]);
    const float c = fmaf(f, co[j], ii * gg);
    cn[j] = c;
    hn[j] = o * tanh_fast(c);
  }

  *reinterpret_cast<float4*>(&ct[cidx]) = make_float4(cn[0], cn[1], cn[2], cn[3]);
  if (!LAST) {
    ushort4 hb;
    hb.x = f2b(hn[0]); hb.y = f2b(hn[1]); hb.z = f2b(hn[2]); hb.w = f2b(hn[3]);
    *reinterpret_cast<ushort4*>(&ht[cidx]) = hb;
  } else {
    *reinterpret_cast<float4*>(&out[cidx]) = make_float4(hn[0], hn[1], hn[2], hn[3]);
    *reinterpret_cast<float4*>(&out[4194304 + cidx]) = make_float4(cn[0], cn[1], cn[2], cn[3]);
  }
}

// ---------------------------------------------------------------- launch
extern "C" void kernel_launch(void* const* d_in, const int* in_sizes, int n_in,
                              void* d_out, int out_size, void* d_ws, size_t ws_size,
                              hipStream_t stream) {
  const float* x = (const float*)d_in[0];   // [4096,1024]
  const float* W = (const float*)d_in[1];   // [4096,1024]
  const float* bW = (const float*)d_in[2];  // [4096]
  const float* U = (const float*)d_in[3];   // [4096,1024]
  const float* bU = (const float*)d_in[4];  // [4096]
  float* out = (float*)d_out;

  char* w = (char*)d_ws;
  const size_t MB = 1ull << 20;
  unsigned short* xb = (unsigned short*)(w + 0 * MB);      // 8 MB
  unsigned short* Wb = (unsigned short*)(w + 8 * MB);      // 8 MB
  unsigned short* Ub = (unsigned short*)(w + 16 * MB);     // 8 MB
  unsigned short* xproj = (unsigned short*)(w + 24 * MB);  // 32 MB [B,4H] bf16
  unsigned short* hproj = (unsigned short*)(w + 56 * MB);  // 32 MB
  float* ct = (float*)(w + 88 * MB);                       // 16 MB
  unsigned short* ht = (unsigned short*)(w + 104 * MB);    // 8 MB

  const int n4 = (4096 * 1024) / 4;
  cast_kernel<<<n4 / 256, 256, 0, stream>>>(x, xb, n4);
  cast_kernel<<<n4 / 256, 256, 0, stream>>>(W, Wb, n4);
  cast_kernel<<<n4 / 256, 256, 0, stream>>>(U, Ub, n4);

  gemm256<<<256, 512, 0, stream>>>(xb, Wb, xproj);
  gates_kernel<true, false><<<4096, 256, 0, stream>>>(xproj, nullptr, bW, bU, ct, ht, nullptr);
  for (int t = 1; t < 8; ++t) {
    gemm256<<<256, 512, 0, stream>>>(ht, Ub, hproj);
    if (t == 7)
      gates_kernel<false, true><<<4096, 256, 0, stream>>>(xproj, hproj, bW, bU, ct, ht, out);
    else
      gates_kernel<false, false><<<4096, 256, 0, stream>>>(xproj, hproj, bW, bU, ct, ht, nullptr);
  }
}

// Round 4
// 428.780 us; speedup vs baseline: 1.3172x; 1.0683x over previous
//
#include <hip/hip_runtime.h>
#include <hip/hip_bf16.h>

typedef __bf16 bf16x8 __attribute__((ext_vector_type(8)));
typedef float f32x4 __attribute__((ext_vector_type(4)));

#define DEVI static __device__ __forceinline__

DEVI void load_lds16(const void* g, void* l) {
  __builtin_amdgcn_global_load_lds(
      (const __attribute__((address_space(1))) void*)g,
      (__attribute__((address_space(3))) void*)l, 16, 0, 0);
}

DEVI unsigned short f2b(float f) { return __bfloat16_as_ushort(__float2bfloat16(f)); }
DEVI float b2f(unsigned short u) {
  union { unsigned int i; float f; } c;
  c.i = ((unsigned int)u) << 16;
  return c.f;
}
DEVI float sigm(float x) { return 1.0f / (1.0f + __expf(-x)); }
DEVI float tanh_fast(float x) { return 2.0f / (1.0f + __expf(-2.0f * x)) - 1.0f; }

// involutive 16B-granule swizzle within a 32KB slot: XOR byte-bits 4-6 with bits 7-9.
DEVI int swz(int L) { return L ^ (((L >> 7) & 7) << 4); }

// ---------------------------------------------------------------- cast fp32->bf16 (identity rows)
__global__ __launch_bounds__(256) void cast_kernel(const float* __restrict__ src,
                                                   unsigned short* __restrict__ dst,
                                                   int n4) {
  const int i = blockIdx.x * 256 + threadIdx.x;
  if (i >= n4) return;
  const float4 v = reinterpret_cast<const float4*>(src)[i];
  ushort4 o;
  o.x = f2b(v.x); o.y = f2b(v.y); o.z = f2b(v.z); o.w = f2b(v.w);
  reinterpret_cast<ushort4*>(dst)[i] = o;
}

// cast + gate-interleave row permute: src row r = g*1024+h  ->  dst row 4h+g.
// src [4096][1024] f32, dst [4096][1024] bf16. 1M threads, 4 f32 each.
__global__ __launch_bounds__(256) void cast_perm_kernel(const float* __restrict__ src,
                                                        unsigned short* __restrict__ dst) {
  const int i = blockIdx.x * 256 + threadIdx.x;  // 0 .. 1M-1
  const int r = i >> 8;        // input row
  const int cw = i & 255;      // float4 chunk within row
  const float4 v = reinterpret_cast<const float4*>(src)[i];
  const int rp = ((r & 1023) << 2) + (r >> 10);  // 4h+g
  ushort4 o;
  o.x = f2b(v.x); o.y = f2b(v.y); o.z = f2b(v.z); o.w = f2b(v.w);
  *reinterpret_cast<ushort4*>(&dst[(size_t)rp * 1024 + (cw << 2)]) = o;
}

// bp[4h+g] = bW[g*1024+h] + bU[g*1024+h]
__global__ __launch_bounds__(256) void bias_prep(const float* __restrict__ bW,
                                                 const float* __restrict__ bU,
                                                 float* __restrict__ bp) {
  const int i = blockIdx.x * 256 + threadIdx.x;  // 0..4095
  const int h = i >> 2, g = i & 3;
  bp[i] = bW[g * 1024 + h] + bU[g * 1024 + h];
}

// ---------------------------------------------------------------- GEMM 256x256 (+ fused gates)
// C[4096,4096] = A[4096,1024] * Bm[4096,1024]^T (bf16 in, fp32 acc)
// K-loop identical to round-3 (verified): 4 LDS slots x 32KB, counted vmcnt(8).
// Epilogue: stage C tile to LDS (bf16, padded stride 264 elems);
//   !FUSED: coalesced 16B stores of the bf16 tile to Cout.
//   FUSED : gate-interleaved cols (4h+g) -> per (b,h): s = acc + xproj + bp;
//           ct' = sig(f)*ct + sig(i)*tanh(g); ht' = sig(o)*tanh(ct').
template <bool FUSED, bool LAST>
__global__ __launch_bounds__(512, 2) void gemm256(
    const unsigned short* __restrict__ A,
    const unsigned short* __restrict__ Bm,
    unsigned short* __restrict__ Cout,         // used if !FUSED
    const unsigned short* __restrict__ xproj,  // used if FUSED (permuted cols)
    const float* __restrict__ bp,              // [4H] permuted combined bias
    float* __restrict__ ct,                    // [B,H] fp32 state (rw)
    unsigned short* __restrict__ htout,        // [B,H] bf16 next-step input
    float* __restrict__ out) {                 // d_out when LAST
  constexpr int K = 1024, N = 4096;
  constexpr int NPH = K / 32;  // 32 phases
  __shared__ unsigned char lds[256 * 528];  // 135168 B >= 4*32768 K-loop use

  const int tid = threadIdx.x;
  const int lane = tid & 63;
  const int wave = tid >> 6;
  const int wr = wave >> 2;  // 0..1 : M half (128 rows)
  const int wc = wave & 3;   // 0..3 : N quarter (64 cols)

  // XCD-aware block swizzle (nwg=256, divisible by 8)
  const int bid = blockIdx.x;
  const int sw = (bid & 7) * 32 + (bid >> 3);
  const int brow = (sw >> 4) * 256;
  const int bcol = (sw & 15) * 256;

  // staging geometry (swizzle via pre-permuted global source, rule #21)
  const int physA0 = tid * 16;
  const int physA1 = 8192 + tid * 16;
  const int physB0 = 16384 + tid * 16;
  const int physB1 = 24576 + tid * 16;
  const int LA0 = swz(physA0), LA1 = swz(physA1);
  const int LB0 = swz(physB0 - 16384), LB1 = swz(physB1 - 16384);
  const unsigned char* pA0 = (const unsigned char*)A + (size_t)(brow + (LA0 >> 6)) * (K * 2) + (LA0 & 63);
  const unsigned char* pA1 = (const unsigned char*)A + (size_t)(brow + (LA1 >> 6)) * (K * 2) + (LA1 & 63);
  const unsigned char* pB0 = (const unsigned char*)Bm + (size_t)(bcol + (LB0 >> 6)) * (K * 2) + (LB0 & 63);
  const unsigned char* pB1 = (const unsigned char*)Bm + (size_t)(bcol + (LB1 >> 6)) * (K * 2) + (LB1 & 63);

  // fragment read offsets (slot-relative), swizzled
  const int s16 = (lane >> 4) * 16;
  int offA[8], offB[4];
#pragma unroll
  for (int m = 0; m < 8; ++m) {
    const int row = wr * 128 + m * 16 + (lane & 15);
    offA[m] = swz(row * 64 + s16);
  }
#pragma unroll
  for (int n = 0; n < 4; ++n) {
    const int row = wc * 64 + n * 16 + (lane & 15);
    offB[n] = 16384 + swz(row * 64 + s16);
  }

  f32x4 acc[8][4] = {};

  auto STAGE = [&](int q) {
    unsigned char* sb = lds + (q & 3) * 32768;
    const size_t kb = (size_t)q * 64;
    load_lds16(pA0 + kb, sb + physA0);
    load_lds16(pA1 + kb, sb + physA1);
    load_lds16(pB0 + kb, sb + physB0);
    load_lds16(pB1 + kb, sb + physB1);
  };

  STAGE(0); STAGE(1); STAGE(2);
  asm volatile("s_waitcnt vmcnt(8)" ::: "memory");
  __builtin_amdgcn_s_barrier();
  __builtin_amdgcn_sched_barrier(0);

  for (int p = 0; p < NPH; ++p) {
    if (p + 3 < NPH) STAGE(p + 3);

    const unsigned char* sl = lds + (p & 3) * 32768;
    bf16x8 af[8], bf[4];
#pragma unroll
    for (int n = 0; n < 4; ++n) bf[n] = *reinterpret_cast<const bf16x8*>(sl + offB[n]);
#pragma unroll
    for (int m = 0; m < 8; ++m) af[m] = *reinterpret_cast<const bf16x8*>(sl + offA[m]);

    __builtin_amdgcn_s_setprio(1);
#pragma unroll
    for (int m = 0; m < 8; ++m)
#pragma unroll
      for (int n = 0; n < 4; ++n)
        acc[m][n] = __builtin_amdgcn_mfma_f32_16x16x32_bf16(af[m], bf[n], acc[m][n], 0, 0, 0);
    __builtin_amdgcn_s_setprio(0);

    if (p < NPH - 1) {
      if (p < NPH - 3)
        asm volatile("s_waitcnt vmcnt(8)" ::: "memory");
      else if (p == NPH - 3)
        asm volatile("s_waitcnt vmcnt(4)" ::: "memory");
      else
        asm volatile("s_waitcnt vmcnt(0)" ::: "memory");
      __builtin_amdgcn_s_barrier();
      __builtin_amdgcn_sched_barrier(0);
    }
  }

  // ---- epilogue: stage bf16 C tile into LDS, padded row stride 264 elems (528B)
  __syncthreads();  // all waves done reading K-loop slots
  unsigned short* cs = (unsigned short*)lds;
  {
    const int c0 = wc * 64 + (lane & 15);
    const int r00 = wr * 128 + ((lane >> 4) << 2);
#pragma unroll
    for (int m = 0; m < 8; ++m)
#pragma unroll
      for (int n = 0; n < 4; ++n) {
        const int rr = r00 + m * 16;
        const int cc = c0 + n * 16;
#pragma unroll
        for (int r = 0; r < 4; ++r) cs[(rr + r) * 264 + cc] = f2b(acc[m][n][r]);
      }
  }
  __syncthreads();

  if constexpr (!FUSED) {
    // coalesced wide stores: 16 granules of 16B per thread
#pragma unroll
    for (int j = 0; j < 16; ++j) {
      const int g = tid + (j << 9);  // 0..8191
      const int row = g >> 5, gc = g & 31;
      const uint4 v = *reinterpret_cast<const uint4*>(&cs[row * 264 + gc * 8]);
      *reinterpret_cast<uint4*>(&Cout[(size_t)(brow + row) * N + bcol + gc * 8]) = v;
    }
  } else {
    const int hbase = bcol >> 2;  // global h start for this block (64 h's)
    for (int j = 0; j < 32; ++j) {
      const int q = tid + (j << 9);  // 0..16383 = 256 rows x 64 h
      const int row = q >> 6;
      const int hh = q & 63;
      const ushort4 pv = *reinterpret_cast<const ushort4*>(&cs[row * 264 + hh * 4]);
      const ushort4 xv = *reinterpret_cast<const ushort4*>(&xproj[(size_t)(brow + row) * N + bcol + hh * 4]);
      const float4 bpv = *reinterpret_cast<const float4*>(&bp[bcol + hh * 4]);
      const int ci = (brow + row) * 1024 + hbase + hh;
      const float c_old = ct[ci];
      const float sf = b2f(pv.x) + b2f(xv.x) + bpv.x;
      const float si = b2f(pv.y) + b2f(xv.y) + bpv.y;
      const float so = b2f(pv.z) + b2f(xv.z) + bpv.z;
      const float sg = b2f(pv.w) + b2f(xv.w) + bpv.w;
      const float f = sigm(sf);
      const float ii = sigm(si);
      const float o = sigm(so);
      const float gg = tanh_fast(sg);
      const float c = fmaf(f, c_old, ii * gg);
      const float h = o * tanh_fast(c);
      ct[ci] = c;
      if constexpr (LAST) {
        out[ci] = h;
        out[4194304 + ci] = c;
      } else {
        htout[ci] = f2b(h);
      }
    }
  }
}

// ---------------------------------------------------------------- first-step gates
// ht = sig(o)*tanh(c), c = sig(i)*tanh(g) (c0 = 0); xproj is gate-interleaved.
__global__ __launch_bounds__(256) void gates_first(
    const unsigned short* __restrict__ xproj, const float* __restrict__ bp,
    float* __restrict__ ct, unsigned short* __restrict__ ht) {
  const int i = blockIdx.x * 256 + threadIdx.x;  // 1M threads
  const int b = i >> 8;
  const int h0 = (i & 255) << 2;
  const size_t xbase = (size_t)b * 4096 + ((size_t)h0 << 2);
  float cn[4], hn[4];
#pragma unroll
  for (int k = 0; k < 4; ++k) {
    const ushort4 pv = *reinterpret_cast<const ushort4*>(&xproj[xbase + k * 4]);
    const float4 bpv = *reinterpret_cast<const float4*>(&bp[(h0 + k) * 4]);
    const float f = sigm(b2f(pv.x) + bpv.x);  (void)f;
    const float ii = sigm(b2f(pv.y) + bpv.y);
    const float o = sigm(b2f(pv.z) + bpv.z);
    const float gg = tanh_fast(b2f(pv.w) + bpv.w);
    const float c = ii * gg;  // f * 0 + i*g
    cn[k] = c;
    hn[k] = o * tanh_fast(c);
  }
  const int ci = b * 1024 + h0;
  *reinterpret_cast<float4*>(&ct[ci]) = make_float4(cn[0], cn[1], cn[2], cn[3]);
  ushort4 hb;
  hb.x = f2b(hn[0]); hb.y = f2b(hn[1]); hb.z = f2b(hn[2]); hb.w = f2b(hn[3]);
  *reinterpret_cast<ushort4*>(&ht[ci]) = hb;
}

// ---------------------------------------------------------------- launch
extern "C" void kernel_launch(void* const* d_in, const int* in_sizes, int n_in,
                              void* d_out, int out_size, void* d_ws, size_t ws_size,
                              hipStream_t stream) {
  const float* x = (const float*)d_in[0];   // [4096,1024]
  const float* W = (const float*)d_in[1];   // [4096,1024]
  const float* bW = (const float*)d_in[2];  // [4096]
  const float* U = (const float*)d_in[3];   // [4096,1024]
  const float* bU = (const float*)d_in[4];  // [4096]
  float* out = (float*)d_out;

  char* w = (char*)d_ws;
  const size_t MB = 1ull << 20;
  unsigned short* xb = (unsigned short*)(w + 0 * MB);      // 8 MB
  unsigned short* Wbp = (unsigned short*)(w + 8 * MB);     // 8 MB (gate-interleaved)
  unsigned short* Ubp = (unsigned short*)(w + 16 * MB);    // 8 MB (gate-interleaved)
  unsigned short* xproj = (unsigned short*)(w + 24 * MB);  // 32 MB [B,4H] bf16 permuted
  float* ct = (float*)(w + 56 * MB);                       // 16 MB
  unsigned short* htA = (unsigned short*)(w + 72 * MB);    // 8 MB
  unsigned short* htB = (unsigned short*)(w + 80 * MB);    // 8 MB
  float* bp = (float*)(w + 88 * MB);                       // 16 KB

  const int n4 = (4096 * 1024) / 4;
  cast_kernel<<<4096, 256, 0, stream>>>(x, xb, n4);
  cast_perm_kernel<<<4096, 256, 0, stream>>>(W, Wbp);
  cast_perm_kernel<<<4096, 256, 0, stream>>>(U, Ubp);
  bias_prep<<<16, 256, 0, stream>>>(bW, bU, bp);

  gemm256<false, false><<<256, 512, 0, stream>>>(xb, Wbp, xproj, nullptr, nullptr, nullptr, nullptr, nullptr);
  gates_first<<<4096, 256, 0, stream>>>(xproj, bp, ct, htA);

  const unsigned short* hin = htA;
  unsigned short* hout = htB;
  for (int t = 1; t <= 6; ++t) {
    gemm256<true, false><<<256, 512, 0, stream>>>(hin, Ubp, nullptr, xproj, bp, ct, hout, nullptr);
    const unsigned short* tmp = hout;
    hout = (unsigned short*)hin;
    hin = tmp;
  }
  gemm256<true, true><<<256, 512, 0, stream>>>(hin, Ubp, nullptr, xproj, bp, ct, nullptr, out);
}

// Round 5
// 426.477 us; speedup vs baseline: 1.3243x; 1.0054x over previous
//
#include <hip/hip_runtime.h>
#include <hip/hip_bf16.h>

typedef __bf16 bf16x8 __attribute__((ext_vector_type(8)));
typedef float f32x4 __attribute__((ext_vector_type(4)));

#define DEVI static __device__ __forceinline__

DEVI void load_lds16(const void* g, void* l) {
  __builtin_amdgcn_global_load_lds(
      (const __attribute__((address_space(1))) void*)g,
      (__attribute__((address_space(3))) void*)l, 16, 0, 0);
}

DEVI unsigned short f2b(float f) { return __bfloat16_as_ushort(__float2bfloat16(f)); }
DEVI float b2f(unsigned short u) {
  union { unsigned int i; float f; } c;
  c.i = ((unsigned int)u) << 16;
  return c.f;
}
DEVI float sigm(float x) { return 1.0f / (1.0f + __expf(-x)); }
DEVI float tanh_fast(float x) { return 2.0f / (1.0f + __expf(-2.0f * x)) - 1.0f; }

// involutive 16B-granule swizzle within a 32KB slot: XOR byte-bits 4-6 with bits 7-9.
DEVI int swz(int L) { return L ^ (((L >> 7) & 7) << 4); }

// ---------------------------------------------------------------- cast fp32->bf16 (identity rows)
__global__ __launch_bounds__(256) void cast_kernel(const float* __restrict__ src,
                                                   unsigned short* __restrict__ dst,
                                                   int n4) {
  const int i = blockIdx.x * 256 + threadIdx.x;
  if (i >= n4) return;
  const float4 v = reinterpret_cast<const float4*>(src)[i];
  ushort4 o;
  o.x = f2b(v.x); o.y = f2b(v.y); o.z = f2b(v.z); o.w = f2b(v.w);
  reinterpret_cast<ushort4*>(dst)[i] = o;
}

// cast + gate-interleave row permute: src row r = g*1024+h  ->  dst row 4h+g.
__global__ __launch_bounds__(256) void cast_perm_kernel(const float* __restrict__ src,
                                                        unsigned short* __restrict__ dst) {
  const int i = blockIdx.x * 256 + threadIdx.x;  // 0 .. 1M-1
  const int r = i >> 8;        // input row
  const int cw = i & 255;      // float4 chunk within row
  const float4 v = reinterpret_cast<const float4*>(src)[i];
  const int rp = ((r & 1023) << 2) + (r >> 10);  // 4h+g
  ushort4 o;
  o.x = f2b(v.x); o.y = f2b(v.y); o.z = f2b(v.z); o.w = f2b(v.w);
  *reinterpret_cast<ushort4*>(&dst[(size_t)rp * 1024 + (cw << 2)]) = o;
}

// bp[4h+g] = bW[g*1024+h] + bU[g*1024+h]
__global__ __launch_bounds__(256) void bias_prep(const float* __restrict__ bW,
                                                 const float* __restrict__ bU,
                                                 float* __restrict__ bp) {
  const int i = blockIdx.x * 256 + threadIdx.x;  // 0..4095
  const int h = i >> 2, g = i & 3;
  bp[i] = bW[g * 1024 + h] + bU[g * 1024 + h];
}

// ---------------------------------------------------------------- GEMM 256x256 (+ fused gates)
// C[4096,4096] = A[4096,1024] * Bm[4096,1024]^T (bf16 in, fp32 acc)
// 4 LDS slots x 32KB rotation, counted vmcnt (verified r3/r4). K-loop now uses
// the 8-phase-style dual-barrier sub-phases (T3+T4): per 32-K phase, two
// {4-8 ds_read -> B -> lgkm(0) -> 16 MFMA -> B} granules with staging split.
template <bool FUSED, bool LAST>
__global__ __launch_bounds__(512, 2) void gemm256(
    const unsigned short* __restrict__ A,
    const unsigned short* __restrict__ Bm,
    unsigned short* __restrict__ Cout,         // used if !FUSED
    const unsigned short* __restrict__ xproj,  // used if FUSED (permuted cols)
    const float* __restrict__ bp,              // [4H] permuted combined bias
    float* __restrict__ ct,                    // [B,H] fp32 state (rw)
    unsigned short* __restrict__ htout,        // [B,H] bf16 next-step input
    float* __restrict__ out) {                 // d_out when LAST
  constexpr int K = 1024, N = 4096;
  constexpr int NPH = K / 32;  // 32 phases
  __shared__ unsigned char lds[256 * 528];  // 135168 B >= 4*32768 K-loop use

  const int tid = threadIdx.x;
  const int lane = tid & 63;
  const int wave = tid >> 6;
  const int wr = wave >> 2;  // 0..1 : M half (128 rows)
  const int wc = wave & 3;   // 0..3 : N quarter (64 cols)

  // XCD-aware block swizzle (nwg=256, divisible by 8)
  const int bid = blockIdx.x;
  const int sw = (bid & 7) * 32 + (bid >> 3);
  const int brow = (sw >> 4) * 256;
  const int bcol = (sw & 15) * 256;

  // staging geometry (swizzle via pre-permuted global source, rule #21)
  const int physA0 = tid * 16;
  const int physA1 = 8192 + tid * 16;
  const int physB0 = 16384 + tid * 16;
  const int physB1 = 24576 + tid * 16;
  const int LA0 = swz(physA0), LA1 = swz(physA1);
  const int LB0 = swz(physB0 - 16384), LB1 = swz(physB1 - 16384);
  const unsigned char* pA0 = (const unsigned char*)A + (size_t)(brow + (LA0 >> 6)) * (K * 2) + (LA0 & 63);
  const unsigned char* pA1 = (const unsigned char*)A + (size_t)(brow + (LA1 >> 6)) * (K * 2) + (LA1 & 63);
  const unsigned char* pB0 = (const unsigned char*)Bm + (size_t)(bcol + (LB0 >> 6)) * (K * 2) + (LB0 & 63);
  const unsigned char* pB1 = (const unsigned char*)Bm + (size_t)(bcol + (LB1 >> 6)) * (K * 2) + (LB1 & 63);

  // fragment read offsets (slot-relative), swizzled
  const int s16 = (lane >> 4) * 16;
  int offA[8], offB[4];
#pragma unroll
  for (int m = 0; m < 8; ++m) {
    const int row = wr * 128 + m * 16 + (lane & 15);
    offA[m] = swz(row * 64 + s16);
  }
#pragma unroll
  for (int n = 0; n < 4; ++n) {
    const int row = wc * 64 + n * 16 + (lane & 15);
    offB[n] = 16384 + swz(row * 64 + s16);
  }

  f32x4 acc[8][4] = {};

  auto STAGE_A = [&](int q) {
    unsigned char* sb = lds + (q & 3) * 32768;
    const size_t kb = (size_t)q * 64;
    load_lds16(pA0 + kb, sb + physA0);
    load_lds16(pA1 + kb, sb + physA1);
  };
  auto STAGE_B = [&](int q) {
    unsigned char* sb = lds + (q & 3) * 32768;
    const size_t kb = (size_t)q * 64;
    load_lds16(pB0 + kb, sb + physB0);
    load_lds16(pB1 + kb, sb + physB1);
  };

  // prologue: 3 slots in flight (12 loads); vmcnt(8) retires slot 0 (oldest 4)
  STAGE_A(0); STAGE_B(0); STAGE_A(1); STAGE_B(1); STAGE_A(2); STAGE_B(2);
  asm volatile("s_waitcnt vmcnt(8)" ::: "memory");
  __builtin_amdgcn_s_barrier();
  __builtin_amdgcn_sched_barrier(0);

  for (int p = 0; p < NPH; ++p) {
    const unsigned char* sl = lds + (p & 3) * 32768;
    bf16x8 af[8], bf[4];

    // ---------------- sub-phase A: 8 reads + A-half stage | 16 MFMA
#pragma unroll
    for (int n = 0; n < 4; ++n) bf[n] = *reinterpret_cast<const bf16x8*>(sl + offB[n]);
#pragma unroll
    for (int m = 0; m < 4; ++m) af[m] = *reinterpret_cast<const bf16x8*>(sl + offA[m]);
    if (p + 3 < NPH) STAGE_A(p + 3);
    __builtin_amdgcn_sched_barrier(0);
    __builtin_amdgcn_s_barrier();  // B1
    asm volatile("s_waitcnt lgkmcnt(0)" ::: "memory");
    __builtin_amdgcn_sched_barrier(0);
    __builtin_amdgcn_s_setprio(1);
#pragma unroll
    for (int m = 0; m < 4; ++m)
#pragma unroll
      for (int n = 0; n < 4; ++n)
        acc[m][n] = __builtin_amdgcn_mfma_f32_16x16x32_bf16(af[m], bf[n], acc[m][n], 0, 0, 0);
    __builtin_amdgcn_s_setprio(0);
    __builtin_amdgcn_sched_barrier(0);
    __builtin_amdgcn_s_barrier();  // B2

    // ---------------- sub-phase B: 4 reads + B-half stage | 16 MFMA
#pragma unroll
    for (int m = 4; m < 8; ++m) af[m] = *reinterpret_cast<const bf16x8*>(sl + offA[m]);
    if (p + 3 < NPH) STAGE_B(p + 3);
    __builtin_amdgcn_sched_barrier(0);
    __builtin_amdgcn_s_barrier();  // B3
    asm volatile("s_waitcnt lgkmcnt(0)" ::: "memory");
    __builtin_amdgcn_sched_barrier(0);
    __builtin_amdgcn_s_setprio(1);
#pragma unroll
    for (int m = 4; m < 8; ++m)
#pragma unroll
      for (int n = 0; n < 4; ++n)
        acc[m][n] = __builtin_amdgcn_mfma_f32_16x16x32_bf16(af[m], bf[n], acc[m][n], 0, 0, 0);
    __builtin_amdgcn_s_setprio(0);

    if (p < NPH - 1) {
      // gate next phase's slot: retire slot p+1 (own loads), then barrier so
      // ALL waves' slot-(p+1) stages are retired before any wave reads it.
      if (p < NPH - 3)
        asm volatile("s_waitcnt vmcnt(8)" ::: "memory");
      else if (p == NPH - 3)
        asm volatile("s_waitcnt vmcnt(4)" ::: "memory");
      else
        asm volatile("s_waitcnt vmcnt(0)" ::: "memory");
      __builtin_amdgcn_s_barrier();  // B4
      __builtin_amdgcn_sched_barrier(0);
    }
  }

  // ---- epilogue: stage bf16 C tile into LDS, padded row stride 264 elems (528B)
  __syncthreads();  // all waves done reading K-loop slots (full waitcnt drain)
  unsigned short* cs = (unsigned short*)lds;
  {
    const int c0 = wc * 64 + (lane & 15);
    const int r00 = wr * 128 + ((lane >> 4) << 2);
#pragma unroll
    for (int m = 0; m < 8; ++m)
#pragma unroll
      for (int n = 0; n < 4; ++n) {
        const int rr = r00 + m * 16;
        const int cc = c0 + n * 16;
#pragma unroll
        for (int r = 0; r < 4; ++r) cs[(rr + r) * 264 + cc] = f2b(acc[m][n][r]);
      }
  }
  __syncthreads();

  if constexpr (!FUSED) {
    // coalesced wide stores: 16 granules of 16B per thread
#pragma unroll
    for (int j = 0; j < 16; ++j) {
      const int g = tid + (j << 9);  // 0..8191
      const int row = g >> 5, gc = g & 31;
      const uint4 v = *reinterpret_cast<const uint4*>(&cs[row * 264 + gc * 8]);
      *reinterpret_cast<uint4*>(&Cout[(size_t)(brow + row) * N + bcol + gc * 8]) = v;
    }
  } else {
    const int hbase = bcol >> 2;  // global h start for this block (64 h's)
#pragma unroll 4
    for (int j = 0; j < 32; ++j) {
      const int q = tid + (j << 9);  // 0..16383 = 256 rows x 64 h
      const int row = q >> 6;
      const int hh = q & 63;
      const ushort4 pv = *reinterpret_cast<const ushort4*>(&cs[row * 264 + hh * 4]);
      const ushort4 xv = *reinterpret_cast<const ushort4*>(&xproj[(size_t)(brow + row) * N + bcol + hh * 4]);
      const float4 bpv = *reinterpret_cast<const float4*>(&bp[bcol + hh * 4]);
      const int ci = (brow + row) * 1024 + hbase + hh;
      const float c_old = ct[ci];
      const float sf = b2f(pv.x) + b2f(xv.x) + bpv.x;
      const float si = b2f(pv.y) + b2f(xv.y) + bpv.y;
      const float so = b2f(pv.z) + b2f(xv.z) + bpv.z;
      const float sg = b2f(pv.w) + b2f(xv.w) + bpv.w;
      const float f = sigm(sf);
      const float ii = sigm(si);
      const float o = sigm(so);
      const float gg = tanh_fast(sg);
      const float c = fmaf(f, c_old, ii * gg);
      const float h = o * tanh_fast(c);
      ct[ci] = c;
      if constexpr (LAST) {
        out[ci] = h;
        out[4194304 + ci] = c;
      } else {
        htout[ci] = f2b(h);
      }
    }
  }
}

// ---------------------------------------------------------------- first-step gates
__global__ __launch_bounds__(256) void gates_first(
    const unsigned short* __restrict__ xproj, const float* __restrict__ bp,
    float* __restrict__ ct, unsigned short* __restrict__ ht) {
  const int i = blockIdx.x * 256 + threadIdx.x;  // 1M threads
  const int b = i >> 8;
  const int h0 = (i & 255) << 2;
  const size_t xbase = (size_t)b * 4096 + ((size_t)h0 << 2);
  float cn[4], hn[4];
#pragma unroll
  for (int k = 0; k < 4; ++k) {
    const ushort4 pv = *reinterpret_cast<const ushort4*>(&xproj[xbase + k * 4]);
    const float4 bpv = *reinterpret_cast<const float4*>(&bp[(h0 + k) * 4]);
    const float ii = sigm(b2f(pv.y) + bpv.y);
    const float o = sigm(b2f(pv.z) + bpv.z);
    const float gg = tanh_fast(b2f(pv.w) + bpv.w);
    const float c = ii * gg;  // f * 0 + i*g
    cn[k] = c;
    hn[k] = o * tanh_fast(c);
  }
  const int ci = b * 1024 + h0;
  *reinterpret_cast<float4*>(&ct[ci]) = make_float4(cn[0], cn[1], cn[2], cn[3]);
  ushort4 hb;
  hb.x = f2b(hn[0]); hb.y = f2b(hn[1]); hb.z = f2b(hn[2]); hb.w = f2b(hn[3]);
  *reinterpret_cast<ushort4*>(&ht[ci]) = hb;
}

// ---------------------------------------------------------------- launch
extern "C" void kernel_launch(void* const* d_in, const int* in_sizes, int n_in,
                              void* d_out, int out_size, void* d_ws, size_t ws_size,
                              hipStream_t stream) {
  const float* x = (const float*)d_in[0];   // [4096,1024]
  const float* W = (const float*)d_in[1];   // [4096,1024]
  const float* bW = (const float*)d_in[2];  // [4096]
  const float* U = (const float*)d_in[3];   // [4096,1024]
  const float* bU = (const float*)d_in[4];  // [4096]
  float* out = (float*)d_out;

  char* w = (char*)d_ws;
  const size_t MB = 1ull << 20;
  unsigned short* xb = (unsigned short*)(w + 0 * MB);      // 8 MB
  unsigned short* Wbp = (unsigned short*)(w + 8 * MB);     // 8 MB (gate-interleaved)
  unsigned short* Ubp = (unsigned short*)(w + 16 * MB);    // 8 MB (gate-interleaved)
  unsigned short* xproj = (unsigned short*)(w + 24 * MB);  // 32 MB [B,4H] bf16 permuted
  float* ct = (float*)(w + 56 * MB);                       // 16 MB
  unsigned short* htA = (unsigned short*)(w + 72 * MB);    // 8 MB
  unsigned short* htB = (unsigned short*)(w + 80 * MB);    // 8 MB
  float* bp = (float*)(w + 88 * MB);                       // 16 KB

  const int n4 = (4096 * 1024) / 4;
  cast_kernel<<<4096, 256, 0, stream>>>(x, xb, n4);
  cast_perm_kernel<<<4096, 256, 0, stream>>>(W, Wbp);
  cast_perm_kernel<<<4096, 256, 0, stream>>>(U, Ubp);
  bias_prep<<<16, 256, 0, stream>>>(bW, bU, bp);

  gemm256<false, false><<<256, 512, 0, stream>>>(xb, Wbp, xproj, nullptr, nullptr, nullptr, nullptr, nullptr);
  gates_first<<<4096, 256, 0, stream>>>(xproj, bp, ct, htA);

  const unsigned short* hin = htA;
  unsigned short* hout = htB;
  for (int t = 1; t <= 6; ++t) {
    gemm256<true, false><<<256, 512, 0, stream>>>(hin, Ubp, nullptr, xproj, bp, ct, hout, nullptr);
    const unsigned short* tmp = hout;
    hout = (unsigned short*)hin;
    hin = tmp;
  }
  gemm256<true, true><<<256, 512, 0, stream>>>(hin, Ubp, nullptr, xproj, bp, ct, nullptr, out);
}